// Round 4
// baseline (490.882 us; speedup 1.0000x reference)
//
#include <hip/hip_runtime.h>

// Swin window attention, register-resident MFMA pipeline. 1 block (6 waves) per
// window; wave w owns head w end-to-end. B=4096, N=64, C=180, H=6, D=30(pad 32).
//
// Round-4 change vs round-3: cap total regs <=128 (__launch_bounds__(384,4))
// so TWO blocks co-reside per CU (12 waves). v-pass deferred until after
// softmax so the peak live set is the QK-pass (acc 64 + xf 16), not
// acc + persistent v fragments.
//
// d_ws (prep_kernel fills every launch):
//   [0)       wqkvT  bf16 [576][192]  oc = h*96 + sec*32 + d  (sec: 0=q,1=k,2=v)
//   [221184)  wprojT bf16 [192][192]  n-major
//   [294912)  relb   f32  [6][64][64] pre-gathered rel-pos bias
//
// LDS: one [64][200] short buffer (x bf16, later z bf16). 25.6 KB.
//
// Fragment-permutation trick: MFMA contracts A-slot(g,s) with B-slot(g,s); both
// q/k fragments carry d(g,s) = 16*(s>=4)+4g+(s&3) (a bijection on [0,32)) and
// P/V fragments carry j(g,s,k2) = 32k2+16*(s>=4)+4g+(s&3) (bijection on [0,64))
// -- identical on both operands, so no shuffles are needed anywhere.

typedef __bf16 bf16;
typedef bf16 bf16x8 __attribute__((ext_vector_type(8)));
typedef float f32x4 __attribute__((ext_vector_type(4)));

#define MFMA(a, b, c) __builtin_amdgcn_mfma_f32_16x16x32_bf16(a, b, c, 0, 0, 0)

__global__ void prep_kernel(const float* __restrict__ wqkv,
                            const float* __restrict__ wproj,
                            const float* __restrict__ btab,
                            bf16* __restrict__ wqkvT,
                            bf16* __restrict__ wprojT,
                            float* __restrict__ relb)
{
    const int idx = blockIdx.x * 256 + threadIdx.x;
    if (idx < 110592) {                          // wqkvT [576][192]
        const int oc = idx / 192, kk = idx - oc * 192;
        const int h = oc / 96, r = oc - h * 96;
        const int sec = r >> 5, d = r & 31;
        wqkvT[idx] = (bf16)((kk < 180 && d < 30) ? wqkv[kk * 540 + sec * 180 + h * 30 + d] : 0.f);
    } else if (idx < 147456) {                   // wprojT [192][192]
        const int r = idx - 110592;
        const int n = r / 192, k = r - n * 192;
        wprojT[r] = (bf16)((n < 180 && k < 180) ? wproj[k * 180 + n] : 0.f);
    } else if (idx < 172032) {                   // relb [6][64][64]
        const int r = idx - 147456;
        const int h = r >> 12;
        const int ij = r & 4095;
        const int i = ij >> 6, j = ij & 63;
        const int rel = ((i >> 3) - (j >> 3) + 7) * 15 + ((i & 7) - (j & 7) + 7);
        relb[r] = btab[rel * 6 + h];
    }
}

__global__ __launch_bounds__(384, 4)
void swin_mfma(const float* __restrict__ xg_all,
               const float* __restrict__ mask_all,
               const float* __restrict__ bproj,
               const bf16* __restrict__ wqkvT,
               const bf16* __restrict__ wprojT,
               const float* __restrict__ relb,
               float* __restrict__ outg)
{
    __shared__ __align__(16) short xb[64 * 200];   // x bf16, later z bf16

    const int b    = blockIdx.x;
    const int tid  = threadIdx.x;
    const int w    = tid >> 6;                     // wave = head, 0..5
    const int lane = tid & 63;
    const int l15  = lane & 15;
    const int g    = lane >> 4;                    // 0..3

    const float* xg    = xg_all + (size_t)b * 11520;
    const float* maskw = mask_all + (size_t)(b & 1023) * 4096;

    // ---- phase 1: x -> bf16 xb[i][c], zero pad cols [180..200)
    for (int e = tid; e < 640; e += 384) {
        const int i = e / 10;
        ((unsigned*)(xb + i * 200 + 180))[e - i * 10] = 0u;
    }
    for (int e = tid; e < 5760; e += 384) {        // 90 float2 per row
        const int i = e / 90;
        const int c = 2 * e - i * 180;
        const float2 v = *reinterpret_cast<const float2*>(xg + 2 * e);
        const unsigned lo = (unsigned)__builtin_bit_cast(unsigned short, (bf16)v.x);
        const unsigned hi = (unsigned)__builtin_bit_cast(unsigned short, (bf16)v.y);
        *reinterpret_cast<unsigned*>(xb + i * 200 + c) = lo | (hi << 16);
    }
    __syncthreads();

    const bf16* wqh = wqkvT + (size_t)(w * 96) * 192;
    const int rowoff = l15 * 192 + 8 * g;

    // ---- phase 2a: q,k for head w (swapped mfma: lane=token, regs=channels)
    bf16x8 qf[4], kf[4];                           // slot s <-> d = 16*(s>=4)+4g+(s&3)
    {
        f32x4 aqk[4][4];                           // [ct][tt] ct: q0,q1,k0,k1
        #pragma unroll
        for (int ct = 0; ct < 4; ct++)
            #pragma unroll
            for (int tt = 0; tt < 4; tt++) aqk[ct][tt] = (f32x4)0.f;
        for (int ks = 0; ks < 6; ks++) {
            bf16x8 xf[4];
            #pragma unroll
            for (int tt = 0; tt < 4; tt++)
                xf[tt] = *reinterpret_cast<const bf16x8*>(xb + (16 * tt + l15) * 200 + 32 * ks + 8 * g);
            #pragma unroll
            for (int ct = 0; ct < 4; ct++) {
                const bf16x8 wf = *reinterpret_cast<const bf16x8*>(wqh + ct * 16 * 192 + rowoff + 32 * ks);
                #pragma unroll
                for (int tt = 0; tt < 4; tt++)
                    aqk[ct][tt] = MFMA(wf, xf[tt], aqk[ct][tt]);
            }
        }
        #pragma unroll
        for (int it = 0; it < 4; it++)
            #pragma unroll
            for (int s = 0; s < 8; s++) {
                qf[it][s] = (bf16)(aqk[s >> 2][it][s & 3] * 0.18257418583505537f);
                kf[it][s] = (bf16)(aqk[2 + (s >> 2)][it][s & 3]);
            }
    }

    // ---- phase 3: QK^T (K=32, one mfma per tile pair) + softmax, it-sequential
    bf16x8 pf[4][2];                               // [it][k2]
    {
        const float* relh = relb + w * 4096;
        #pragma unroll
        for (int it = 0; it < 4; it++) {
            f32x4 stj[4];                          // j = 16jt+4g+r, i = 16it+l15
            #pragma unroll
            for (int jt = 0; jt < 4; jt++) stj[jt] = MFMA(kf[jt], qf[it], (f32x4)0.f);

            const int i = 16 * it + l15;
            const float* rbb = relh + i * 64 + 4 * g;
            const float* mkb = maskw + i * 64 + 4 * g;
            float mx = -1e30f;
            #pragma unroll
            for (int jt = 0; jt < 4; jt++) {
                const float4 rb = *reinterpret_cast<const float4*>(rbb + 16 * jt);
                const float4 mk = *reinterpret_cast<const float4*>(mkb + 16 * jt);
                stj[jt][0] += rb.x + mk.x;
                stj[jt][1] += rb.y + mk.y;
                stj[jt][2] += rb.z + mk.z;
                stj[jt][3] += rb.w + mk.w;
                #pragma unroll
                for (int r = 0; r < 4; r++) mx = fmaxf(mx, stj[jt][r]);
            }
            mx = fmaxf(mx, __shfl_xor(mx, 16));
            mx = fmaxf(mx, __shfl_xor(mx, 32));
            float sum = 0.f;
            #pragma unroll
            for (int jt = 0; jt < 4; jt++)
                #pragma unroll
                for (int r = 0; r < 4; r++) {
                    const float e = __expf(stj[jt][r] - mx);
                    stj[jt][r] = e;
                    sum += e;
                }
            sum += __shfl_xor(sum, 16);
            sum += __shfl_xor(sum, 32);
            const float inv = 1.0f / sum;
            #pragma unroll
            for (int k2 = 0; k2 < 2; k2++)
                #pragma unroll
                for (int s = 0; s < 8; s++)
                    pf[it][k2][s] = (bf16)(stj[2 * k2 + (s >> 2)][s & 3] * inv);
        }
    }

    // ---- phase 2b (deferred): v (normal mfma: lane=channel, regs=tokens)
    bf16x8 vf[2][2];                               // [cv][k2], slot s <-> token 32k2+16*(s>=4)+4g+(s&3)
    {
        f32x4 av[4][2];                            // [tt][cv]
        #pragma unroll
        for (int tt = 0; tt < 4; tt++) { av[tt][0] = (f32x4)0.f; av[tt][1] = (f32x4)0.f; }
        for (int ks = 0; ks < 6; ks++) {
            bf16x8 xf[4];
            #pragma unroll
            for (int tt = 0; tt < 4; tt++)
                xf[tt] = *reinterpret_cast<const bf16x8*>(xb + (16 * tt + l15) * 200 + 32 * ks + 8 * g);
            #pragma unroll
            for (int cv = 0; cv < 2; cv++) {
                const bf16x8 wf = *reinterpret_cast<const bf16x8*>(wqh + (4 + cv) * 16 * 192 + rowoff + 32 * ks);
                #pragma unroll
                for (int tt = 0; tt < 4; tt++)
                    av[tt][cv] = MFMA(xf[tt], wf, av[tt][cv]);
            }
        }
        #pragma unroll
        for (int cv = 0; cv < 2; cv++)
            #pragma unroll
            for (int k2 = 0; k2 < 2; k2++)
                #pragma unroll
                for (int s = 0; s < 8; s++)
                    vf[cv][k2][s] = (bf16)(av[2 * k2 + (s >> 2)][cv][s & 3]);
    }

    // ---- phase 4: PV, all in registers
    f32x4 zacc[4][2];                              // [it][cv]: z[16it+4g+r][16cv+l15]
    #pragma unroll
    for (int it = 0; it < 4; it++) { zacc[it][0] = (f32x4)0.f; zacc[it][1] = (f32x4)0.f; }
    #pragma unroll
    for (int k2 = 0; k2 < 2; k2++)
        #pragma unroll
        for (int cv = 0; cv < 2; cv++)
            #pragma unroll
            for (int it = 0; it < 4; it++)
                zacc[it][cv] = MFMA(pf[it][k2], vf[cv][k2], zacc[it][cv]);

    __syncthreads();                               // all waves done reading xb
    // z -> zb (aliases xb; pad cols [180..200) still zero from phase 1)
    #pragma unroll
    for (int cv = 0; cv < 2; cv++) {
        const int d = 16 * cv + l15;
        if (d < 30) {
            #pragma unroll
            for (int it = 0; it < 4; it++)
                #pragma unroll
                for (int r = 0; r < 4; r++)
                    xb[(16 * it + 4 * g + r) * 200 + w * 30 + d] =
                        __builtin_bit_cast(short, (bf16)zacc[it][cv][r]);
        }
    }
    __syncthreads();

    // ---- phase 5: proj GEMM + bias -> out
    f32x4 pa[4][2];
    #pragma unroll
    for (int mt = 0; mt < 4; mt++) { pa[mt][0] = (f32x4)0.f; pa[mt][1] = (f32x4)0.f; }
    for (int ks = 0; ks < 6; ks++) {
        bf16x8 zf[4];
        #pragma unroll
        for (int mt = 0; mt < 4; mt++)
            zf[mt] = *reinterpret_cast<const bf16x8*>(xb + (16 * mt + l15) * 200 + 32 * ks + 8 * g);
        #pragma unroll
        for (int q2 = 0; q2 < 2; q2++) {
            const bf16x8 wf = *reinterpret_cast<const bf16x8*>(
                wprojT + ((2 * w + q2) * 16 + l15) * 192 + 32 * ks + 8 * g);
            #pragma unroll
            for (int mt = 0; mt < 4; mt++)
                pa[mt][q2] = MFMA(zf[mt], wf, pa[mt][q2]);
        }
    }
    #pragma unroll
    for (int q2 = 0; q2 < 2; q2++) {
        const int n = (2 * w + q2) * 16 + l15;
        if (n < 180) {
            const float bn = bproj[n];
            float* const ob = outg + (size_t)b * 11520 + n;
            #pragma unroll
            for (int mt = 0; mt < 4; mt++)
                #pragma unroll
                for (int r = 0; r < 4; r++)
                    ob[(16 * mt + 4 * g + r) * 180] = pa[mt][q2][r] + bn;
        }
    }
}

extern "C" void kernel_launch(void* const* d_in, const int* in_sizes, int n_in,
                              void* d_out, int out_size, void* d_ws, size_t ws_size,
                              hipStream_t stream) {
    const float* windows = (const float*)d_in[0];
    const float* mask    = (const float*)d_in[1];
    const float* wqkv    = (const float*)d_in[2];
    const float* btab    = (const float*)d_in[3];
    const float* wproj   = (const float*)d_in[4];
    const float* bproj   = (const float*)d_in[5];

    bf16*  wqkvT  = (bf16*)d_ws;
    bf16*  wprojT = (bf16*)((char*)d_ws + 221184);
    float* relb   = (float*)((char*)d_ws + 294912);

    hipLaunchKernelGGL(prep_kernel, dim3(672), dim3(256), 0, stream,
                       wqkv, wproj, btab, wqkvT, wprojT, relb);
    hipLaunchKernelGGL(swin_mfma, dim3(4096), dim3(384), 0, stream,
                       windows, mask, bproj, wqkvT, wprojT, relb, (float*)d_out);
}

// Round 5
// 341.606 us; speedup vs baseline: 1.4370x; 1.4370x over previous
//
#include <hip/hip_runtime.h>

// Swin window attention, register-resident MFMA pipeline. 1 block (6 waves) per
// window; wave w owns head w end-to-end. B=4096, N=64, C=180, H=6, D=30(pad 32).
//
// Round-5 change vs round-4: the (384,4) reg cap stays, but the program is
// restructured to actually fit 128 unified regs (round 4 spilled ~600 MB/disp):
//   - q-pass and k-pass are separate 32-reg-accumulator passes (was one 64-reg)
//   - sched_barrier(0) pins each phase so the scheduler can't merge live ranges
//
// d_ws (prep_kernel fills every launch):
//   [0)       wqkvT  bf16 [576][192]  oc = h*96 + sec*32 + d  (sec: 0=q,1=k,2=v)
//   [221184)  wprojT bf16 [192][192]  n-major
//   [294912)  relb   f32  [6][64][64] pre-gathered rel-pos bias
//
// LDS: one [64][200] short buffer (x bf16, later z bf16). 25.6 KB.
// [64][200]: row stride 400 B = 100 banks -> 16 consecutive rows span 8 banks
// twice = 2-way conflict = free (m136).
//
// Fragment-permutation trick: MFMA contracts A-slot(g,s) with B-slot(g,s); both
// q/k fragments carry d(g,s) = 16*(s>=4)+4g+(s&3) (a bijection on [0,32)) and
// P/V fragments carry j(g,s,k2) = 32k2+16*(s>=4)+4g+(s&3) (bijection on [0,64))
// -- identical on both operands, so no shuffles are needed anywhere.

typedef __bf16 bf16;
typedef bf16 bf16x8 __attribute__((ext_vector_type(8)));
typedef float f32x4 __attribute__((ext_vector_type(4)));

#define MFMA(a, b, c) __builtin_amdgcn_mfma_f32_16x16x32_bf16(a, b, c, 0, 0, 0)

__global__ void prep_kernel(const float* __restrict__ wqkv,
                            const float* __restrict__ wproj,
                            const float* __restrict__ btab,
                            bf16* __restrict__ wqkvT,
                            bf16* __restrict__ wprojT,
                            float* __restrict__ relb)
{
    const int idx = blockIdx.x * 256 + threadIdx.x;
    if (idx < 110592) {                          // wqkvT [576][192]
        const int oc = idx / 192, kk = idx - oc * 192;
        const int h = oc / 96, r = oc - h * 96;
        const int sec = r >> 5, d = r & 31;
        wqkvT[idx] = (bf16)((kk < 180 && d < 30) ? wqkv[kk * 540 + sec * 180 + h * 30 + d] : 0.f);
    } else if (idx < 147456) {                   // wprojT [192][192]
        const int r = idx - 110592;
        const int n = r / 192, k = r - n * 192;
        wprojT[r] = (bf16)((n < 180 && k < 180) ? wproj[k * 180 + n] : 0.f);
    } else if (idx < 172032) {                   // relb [6][64][64]
        const int r = idx - 147456;
        const int h = r >> 12;
        const int ij = r & 4095;
        const int i = ij >> 6, j = ij & 63;
        const int rel = ((i >> 3) - (j >> 3) + 7) * 15 + ((i & 7) - (j & 7) + 7);
        relb[r] = btab[rel * 6 + h];
    }
}

__global__ __launch_bounds__(384, 4)
void swin_mfma(const float* __restrict__ xg_all,
               const float* __restrict__ mask_all,
               const float* __restrict__ bproj,
               const bf16* __restrict__ wqkvT,
               const bf16* __restrict__ wprojT,
               const float* __restrict__ relb,
               float* __restrict__ outg)
{
    __shared__ __align__(16) short xb[64 * 200];   // x bf16, later z bf16

    const int b    = blockIdx.x;
    const int tid  = threadIdx.x;
    const int w    = tid >> 6;                     // wave = head, 0..5
    const int lane = tid & 63;
    const int l15  = lane & 15;
    const int g    = lane >> 4;                    // 0..3

    const float* xg    = xg_all + (size_t)b * 11520;
    const float* maskw = mask_all + (size_t)(b & 1023) * 4096;

    // ---- phase 1: x -> bf16 xb[i][c], zero pad cols [180..200)
    for (int e = tid; e < 640; e += 384) {
        const int i = e / 10;
        ((unsigned*)(xb + i * 200 + 180))[e - i * 10] = 0u;
    }
    for (int e = tid; e < 5760; e += 384) {        // 90 float2 per row
        const int i = e / 90;
        const int c = 2 * e - i * 180;
        const float2 v = *reinterpret_cast<const float2*>(xg + 2 * e);
        const unsigned lo = (unsigned)__builtin_bit_cast(unsigned short, (bf16)v.x);
        const unsigned hi = (unsigned)__builtin_bit_cast(unsigned short, (bf16)v.y);
        *reinterpret_cast<unsigned*>(xb + i * 200 + c) = lo | (hi << 16);
    }
    __syncthreads();

    const bf16* wqh = wqkvT + (size_t)(w * 96) * 192;
    const int rowoff = l15 * 192 + 8 * g;

    // ---- phase 2q: q for head w (swapped mfma: lane=token, regs=channels)
    bf16x8 qf[4];                                  // slot s <-> d = 16*(s>=4)+4g+(s&3)
    {
        f32x4 aq[2][4];                            // [ct][tt]
        #pragma unroll
        for (int ct = 0; ct < 2; ct++)
            #pragma unroll
            for (int tt = 0; tt < 4; tt++) aq[ct][tt] = (f32x4)0.f;
        for (int ks = 0; ks < 6; ks++) {
            bf16x8 xf[4];
            #pragma unroll
            for (int tt = 0; tt < 4; tt++)
                xf[tt] = *reinterpret_cast<const bf16x8*>(xb + (16 * tt + l15) * 200 + 32 * ks + 8 * g);
            #pragma unroll
            for (int ct = 0; ct < 2; ct++) {
                const bf16x8 wf = *reinterpret_cast<const bf16x8*>(wqh + ct * 16 * 192 + rowoff + 32 * ks);
                #pragma unroll
                for (int tt = 0; tt < 4; tt++)
                    aq[ct][tt] = MFMA(wf, xf[tt], aq[ct][tt]);
            }
        }
        #pragma unroll
        for (int tt = 0; tt < 4; tt++)
            #pragma unroll
            for (int s = 0; s < 8; s++)
                qf[tt][s] = (bf16)(aq[s >> 2][tt][s & 3] * 0.18257418583505537f);
    }
    __builtin_amdgcn_sched_barrier(0);

    // ---- phase 2k: k for head w
    bf16x8 kf[4];
    {
        f32x4 ak[2][4];
        #pragma unroll
        for (int ct = 0; ct < 2; ct++)
            #pragma unroll
            for (int tt = 0; tt < 4; tt++) ak[ct][tt] = (f32x4)0.f;
        for (int ks = 0; ks < 6; ks++) {
            bf16x8 xf[4];
            #pragma unroll
            for (int tt = 0; tt < 4; tt++)
                xf[tt] = *reinterpret_cast<const bf16x8*>(xb + (16 * tt + l15) * 200 + 32 * ks + 8 * g);
            #pragma unroll
            for (int ct = 0; ct < 2; ct++) {
                const bf16x8 wf = *reinterpret_cast<const bf16x8*>(wqh + (2 + ct) * 16 * 192 + rowoff + 32 * ks);
                #pragma unroll
                for (int tt = 0; tt < 4; tt++)
                    ak[ct][tt] = MFMA(wf, xf[tt], ak[ct][tt]);
            }
        }
        #pragma unroll
        for (int tt = 0; tt < 4; tt++)
            #pragma unroll
            for (int s = 0; s < 8; s++)
                kf[tt][s] = (bf16)(ak[s >> 2][tt][s & 3]);
    }
    __builtin_amdgcn_sched_barrier(0);

    // ---- phase 3: QK^T (K=32, one mfma per tile pair) + softmax, it-sequential
    bf16x8 pf[4][2];                               // [it][k2]
    {
        const float* relh = relb + w * 4096;
        #pragma unroll
        for (int it = 0; it < 4; it++) {
            f32x4 stj[4];                          // j = 16jt+4g+r, i = 16it+l15
            #pragma unroll
            for (int jt = 0; jt < 4; jt++) stj[jt] = MFMA(kf[jt], qf[it], (f32x4)0.f);

            const int i = 16 * it + l15;
            const float* rbb = relh + i * 64 + 4 * g;
            const float* mkb = maskw + i * 64 + 4 * g;
            float mx = -1e30f;
            #pragma unroll
            for (int jt = 0; jt < 4; jt++) {
                const float4 rb = *reinterpret_cast<const float4*>(rbb + 16 * jt);
                const float4 mk = *reinterpret_cast<const float4*>(mkb + 16 * jt);
                stj[jt][0] += rb.x + mk.x;
                stj[jt][1] += rb.y + mk.y;
                stj[jt][2] += rb.z + mk.z;
                stj[jt][3] += rb.w + mk.w;
                #pragma unroll
                for (int r = 0; r < 4; r++) mx = fmaxf(mx, stj[jt][r]);
            }
            mx = fmaxf(mx, __shfl_xor(mx, 16));
            mx = fmaxf(mx, __shfl_xor(mx, 32));
            float sum = 0.f;
            #pragma unroll
            for (int jt = 0; jt < 4; jt++)
                #pragma unroll
                for (int r = 0; r < 4; r++) {
                    const float e = __expf(stj[jt][r] - mx);
                    stj[jt][r] = e;
                    sum += e;
                }
            sum += __shfl_xor(sum, 16);
            sum += __shfl_xor(sum, 32);
            const float inv = 1.0f / sum;
            #pragma unroll
            for (int k2 = 0; k2 < 2; k2++)
                #pragma unroll
                for (int s = 0; s < 8; s++)
                    pf[it][k2][s] = (bf16)(stj[2 * k2 + (s >> 2)][s & 3] * inv);
        }
    }
    __builtin_amdgcn_sched_barrier(0);

    // ---- phase 2v (deferred): v (normal mfma: lane=channel, regs=tokens)
    bf16x8 vf[2][2];                               // [cv][k2], slot s <-> token 32k2+16*(s>=4)+4g+(s&3)
    {
        f32x4 av[4][2];                            // [tt][cv]
        #pragma unroll
        for (int tt = 0; tt < 4; tt++) { av[tt][0] = (f32x4)0.f; av[tt][1] = (f32x4)0.f; }
        for (int ks = 0; ks < 6; ks++) {
            bf16x8 xf[4];
            #pragma unroll
            for (int tt = 0; tt < 4; tt++)
                xf[tt] = *reinterpret_cast<const bf16x8*>(xb + (16 * tt + l15) * 200 + 32 * ks + 8 * g);
            #pragma unroll
            for (int cv = 0; cv < 2; cv++) {
                const bf16x8 wf = *reinterpret_cast<const bf16x8*>(wqh + (4 + cv) * 16 * 192 + rowoff + 32 * ks);
                #pragma unroll
                for (int tt = 0; tt < 4; tt++)
                    av[tt][cv] = MFMA(xf[tt], wf, av[tt][cv]);
            }
        }
        #pragma unroll
        for (int cv = 0; cv < 2; cv++)
            #pragma unroll
            for (int k2 = 0; k2 < 2; k2++)
                #pragma unroll
                for (int s = 0; s < 8; s++)
                    vf[cv][k2][s] = (bf16)(av[2 * k2 + (s >> 2)][cv][s & 3]);
    }
    __builtin_amdgcn_sched_barrier(0);

    // ---- phase 4: PV, all in registers
    f32x4 zacc[4][2];                              // [it][cv]: z[16it+4g+r][16cv+l15]
    #pragma unroll
    for (int it = 0; it < 4; it++) { zacc[it][0] = (f32x4)0.f; zacc[it][1] = (f32x4)0.f; }
    #pragma unroll
    for (int k2 = 0; k2 < 2; k2++)
        #pragma unroll
        for (int cv = 0; cv < 2; cv++)
            #pragma unroll
            for (int it = 0; it < 4; it++)
                zacc[it][cv] = MFMA(pf[it][k2], vf[cv][k2], zacc[it][cv]);

    __syncthreads();                               // all waves done reading xb
    // z -> zb (aliases xb; pad cols [180..200) still zero from phase 1)
    #pragma unroll
    for (int cv = 0; cv < 2; cv++) {
        const int d = 16 * cv + l15;
        if (d < 30) {
            #pragma unroll
            for (int it = 0; it < 4; it++)
                #pragma unroll
                for (int r = 0; r < 4; r++)
                    xb[(16 * it + 4 * g + r) * 200 + w * 30 + d] =
                        __builtin_bit_cast(short, (bf16)zacc[it][cv][r]);
        }
    }
    __syncthreads();

    // ---- phase 5: proj GEMM + bias -> out
    f32x4 pa[4][2];
    #pragma unroll
    for (int mt = 0; mt < 4; mt++) { pa[mt][0] = (f32x4)0.f; pa[mt][1] = (f32x4)0.f; }
    for (int ks = 0; ks < 6; ks++) {
        bf16x8 zf[4];
        #pragma unroll
        for (int mt = 0; mt < 4; mt++)
            zf[mt] = *reinterpret_cast<const bf16x8*>(xb + (16 * mt + l15) * 200 + 32 * ks + 8 * g);
        #pragma unroll
        for (int q2 = 0; q2 < 2; q2++) {
            const bf16x8 wf = *reinterpret_cast<const bf16x8*>(
                wprojT + ((2 * w + q2) * 16 + l15) * 192 + 32 * ks + 8 * g);
            #pragma unroll
            for (int mt = 0; mt < 4; mt++)
                pa[mt][q2] = MFMA(zf[mt], wf, pa[mt][q2]);
        }
    }
    #pragma unroll
    for (int q2 = 0; q2 < 2; q2++) {
        const int n = (2 * w + q2) * 16 + l15;
        if (n < 180) {
            const float bn = bproj[n];
            float* const ob = outg + (size_t)b * 11520 + n;
            #pragma unroll
            for (int mt = 0; mt < 4; mt++)
                #pragma unroll
                for (int r = 0; r < 4; r++)
                    ob[(16 * mt + 4 * g + r) * 180] = pa[mt][q2][r] + bn;
        }
    }
}

extern "C" void kernel_launch(void* const* d_in, const int* in_sizes, int n_in,
                              void* d_out, int out_size, void* d_ws, size_t ws_size,
                              hipStream_t stream) {
    const float* windows = (const float*)d_in[0];
    const float* mask    = (const float*)d_in[1];
    const float* wqkv    = (const float*)d_in[2];
    const float* btab    = (const float*)d_in[3];
    const float* wproj   = (const float*)d_in[4];
    const float* bproj   = (const float*)d_in[5];

    bf16*  wqkvT  = (bf16*)d_ws;
    bf16*  wprojT = (bf16*)((char*)d_ws + 221184);
    float* relb   = (float*)((char*)d_ws + 294912);

    hipLaunchKernelGGL(prep_kernel, dim3(672), dim3(256), 0, stream,
                       wqkv, wproj, btab, wqkvT, wprojT, relb);
    hipLaunchKernelGGL(swin_mfma, dim3(4096), dim3(384), 0, stream,
                       windows, mask, bproj, wqkvT, wprojT, relb, (float*)d_out);
}